// Round 7
// baseline (1180.451 us; speedup 1.0000x reference)
//
#include <hip/hip_runtime.h>
#include <math.h>

#define DIM 32

__device__ __forceinline__ unsigned short f2bf(float f) {
    unsigned u = __float_as_uint(f);
    u = (u + 0x7FFF + ((u >> 16) & 1)) >> 16;  // RNE
    return (unsigned short)u;
}
__device__ __forceinline__ float bf2f(unsigned short u) {
    return __uint_as_float(((unsigned)u) << 16);
}

// ---------------- fused degree+count: one u64 atomic per edge ----------------
__global__ void deg_cnt_kernel(const int* __restrict__ col, const float* __restrict__ w,
                               unsigned long long* __restrict__ packed, int E) {
    int e = blockIdx.x * blockDim.x + threadIdx.x;
    if (e < E) {
        unsigned long long wf = (unsigned long long)(w[e] * 4294967296.0f);
        atomicAdd(&packed[col[e]], (1ull << 40) | wf);
    }
}

__global__ void unpack_kernel(const unsigned long long* __restrict__ packed,
                              float* __restrict__ dinv, int N) {
    int n = blockIdx.x * blockDim.x + threadIdx.x;
    if (n < N) {
        unsigned long long p = packed[n];
        float deg = (float)((double)(p & ((1ull << 40) - 1)) * (1.0 / 4294967296.0));
        dinv[n] = rsqrtf(deg + 1.0f);
    }
}

// ---------------- scan (counts read from packed high bits) ----------------
__global__ void scan_block_kernel(const unsigned long long* __restrict__ packed,
                                  int* __restrict__ ptr, int* __restrict__ bsum, int N) {
    __shared__ int s[256];
    int i = blockIdx.x * 256 + threadIdx.x;
    int v = (i < N) ? (int)(packed[i] >> 40) : 0;
    s[threadIdx.x] = v;
    __syncthreads();
#pragma unroll
    for (int off = 1; off < 256; off <<= 1) {
        int t = (threadIdx.x >= off) ? s[threadIdx.x - off] : 0;
        __syncthreads();
        s[threadIdx.x] += t;
        __syncthreads();
    }
    if (i < N) ptr[i] = s[threadIdx.x] - v;
    if (threadIdx.x == 255) bsum[blockIdx.x] = s[255];
}

__global__ void scan_tops_kernel(int* __restrict__ bsum, int* __restrict__ ptr, int nb, int N) {
    if (blockIdx.x == 0 && threadIdx.x == 0) {
        int run = 0;
        for (int b = 0; b < nb; b++) { int t = bsum[b]; bsum[b] = run; run += t; }
        ptr[N] = run;
    }
}

__global__ void scan_add_kernel(int* __restrict__ ptr, const int* __restrict__ bsum,
                                int* __restrict__ cursor, int N) {
    int i = blockIdx.x * blockDim.x + threadIdx.x;
    if (i < N) {
        int p = ptr[i] + bsum[i >> 8];
        ptr[i] = p;
        cursor[i] = p;
    }
}

// ---------------- counting-sort edges by col; norm precomputed; col stored ----------------
__global__ void sort_kernel(const int* __restrict__ row, const int* __restrict__ col,
                            const float* __restrict__ w, const float* __restrict__ dinv,
                            int* __restrict__ cursor, float2* __restrict__ edat,
                            int* __restrict__ ecol, int E) {
    int e = blockIdx.x * blockDim.x + threadIdx.x;
    if (e >= E) return;
    int r = row[e], c = col[e];
    float nm = dinv[r] * w[e] * dinv[c];
    int pos = atomicAdd(&cursor[c], 1);
    edat[pos] = make_float2(__int_as_float(r), nm);
    ecol[pos] = c;
}

// ---------------- pre-MLP + xw0 (bf16) + agg init ----------------
__global__ void pre_kernel(const float* __restrict__ x,
                           const float* __restrict__ W0, const float* __restrict__ b0,
                           const float* __restrict__ W1, const float* __restrict__ b1,
                           const float* __restrict__ Wg, const float* __restrict__ bg,
                           const float* __restrict__ dinv,
                           unsigned short* __restrict__ xwb, float* __restrict__ agg, int N) {
    int tid = blockIdx.x * blockDim.x + threadIdx.x;
    if (tid >= N * DIM) return;
    int n = tid >> 5, d = tid & 31;
    float xv = x[n];
    float acc = b1[d];
#pragma unroll
    for (int k = 0; k < DIM; k++) {
        float h0 = fmaxf(xv * W0[k] + b0[k], 0.0f);
        acc += h0 * W1[k * DIM + d];
    }
    float h = fmaxf(acc, 0.0f);
    float o = 0.0f;
#pragma unroll
    for (int k = 0; k < DIM; k++) {
        float hk = __shfl(h, k, 32);
        o += hk * Wg[k * DIM + d];
    }
    float di = dinv[n];
    xwb[tid] = f2bf(o);
    agg[tid] = o * di * di + bg[d];  // self-loop + bias; edges added by edge_kernel
}

// ---------------- layer boundary: relu(agg) @ Wg -> xwb ; agg := o*di^2 + b (IN PLACE) ----------------
__global__ void mid_kernel(float* __restrict__ agg, const float* __restrict__ Wg,
                           const float* __restrict__ bg, const float* __restrict__ dinv,
                           unsigned short* __restrict__ xwb, int N) {
    int tid = blockIdx.x * blockDim.x + threadIdx.x;
    if (tid >= N * DIM) return;
    int n = tid >> 5, d = tid & 31;
    float h = fmaxf(agg[tid], 0.0f);
    float o = 0.0f;
#pragma unroll
    for (int k = 0; k < DIM; k++) {
        float hk = __shfl(h, k, 32);
        o += hk * Wg[k * DIM + d];
    }
    float di = dinv[n];
    xwb[tid] = f2bf(o);
    agg[tid] = o * di * di + bg[d];
}

// ---------------- edge-parallel gather + segmented reduce + merged atomics ----------------
// wave = 4 consecutive col-sorted edges x 16 lanes (2 bf16 dims per lane).
__global__ void edge_kernel(const unsigned short* __restrict__ xwb,
                            const float2* __restrict__ edat, const int* __restrict__ ecol,
                            float* __restrict__ agg, int E) {
    int t = blockIdx.x * blockDim.x + threadIdx.x;
    int lane = threadIdx.x & 63;
    int q = lane >> 4;        // edge slot 0..3
    int dg = lane & 15;       // dim group: dims 2dg, 2dg+1
    int wv = t >> 6;          // global wave id
    int e = wv * 4 + q;
    bool ev = e < E;
    int ec = ev ? e : E - 1;
    float2 rec = edat[ec];    // broadcast within 16-lane group; 32B coalesced per wave
    int c = ecol[ec];
    int r = __float_as_int(rec.x);
    float nm = ev ? rec.y : 0.0f;
    // one vmem instr: 4 random 64-B rows per wave
    unsigned u = *(const unsigned*)(xwb + (size_t)r * DIM + dg * 2);
    float a0 = nm * bf2f((unsigned short)(u & 0xFFFF));
    float a1 = nm * bf2f((unsigned short)(u >> 16));
    // segmented inclusive scan by col across the 4 edge slots
#pragma unroll
    for (int off = 1; off < 4; off <<= 1) {
        int src = (lane - off * 16) & 63;
        float s0 = __shfl(a0, src, 64);
        float s1 = __shfl(a1, src, 64);
        int cs = __shfl(c, src, 64);
        if (q >= off && cs == c) { a0 += s0; a1 += s1; }
    }
    // tail lane of each col-run stores the run's partial sum
    int cn = __shfl(c, (lane + 16) & 63, 64);
    bool tail = (q == 3) || (cn != c) || (e + 1 >= E);
    if (ev && tail) {
        size_t o = (size_t)c * DIM + dg * 2;
        atomicAdd(&agg[o], a0);
        atomicAdd(&agg[o + 1], a1);
    }
}

// ---------------- mean pool (relu fused) ----------------
__global__ void pool_kernel(const float* __restrict__ agg, const int* __restrict__ batch,
                            float* __restrict__ sums, float* __restrict__ gcnt, int N) {
    int tid = blockIdx.x * blockDim.x + threadIdx.x;
    if (tid >= N * DIM) return;
    int n = tid >> 5, d = tid & 31;
    int g = batch[n];
    atomicAdd(&sums[g * DIM + d], fmaxf(agg[tid], 0.0f));
    if (d == 0) atomicAdd(&gcnt[g], 1.0f);
}

// ---------------- post-MLP ----------------
__global__ void postmlp_kernel(const float* __restrict__ sums, const float* __restrict__ gcnt,
                               const float* __restrict__ W0, const float* __restrict__ b0,
                               const float* __restrict__ W1, const float* __restrict__ b1,
                               float* __restrict__ out, int G) {
    int g = blockIdx.x * blockDim.x + threadIdx.x;
    if (g >= G) return;
    float c = fmaxf(gcnt[g], 1.0f);
    float inv = 1.0f / c;
    float gv[DIM];
#pragma unroll
    for (int k = 0; k < DIM; k++) gv[k] = sums[g * DIM + k] * inv;
    float acc = b1[0];
#pragma unroll
    for (int j = 0; j < DIM; j++) {
        float p = b0[j];
#pragma unroll
        for (int k = 0; k < DIM; k++) p += gv[k] * W0[k * DIM + j];
        p = fmaxf(p, 0.0f);
        acc += p * W1[j];
    }
    out[g] = 1.0f / (1.0f + expf(-acc));
}

extern "C" void kernel_launch(void* const* d_in, const int* in_sizes, int n_in,
                              void* d_out, int out_size, void* d_ws, size_t ws_size,
                              hipStream_t stream) {
    const float* x   = (const float*)d_in[0];
    const int*   ei  = (const int*)d_in[1];
    const float* ew  = (const float*)d_in[2];
    const int*   bat = (const int*)d_in[3];
    const float* Wpre0 = (const float*)d_in[4];
    const float* bpre0 = (const float*)d_in[5];
    const float* Wpre1 = (const float*)d_in[6];
    const float* bpre1 = (const float*)d_in[7];
    const float* Wg[3]  = {(const float*)d_in[8],  (const float*)d_in[10], (const float*)d_in[12]};
    const float* bg[3]  = {(const float*)d_in[9],  (const float*)d_in[11], (const float*)d_in[13]};
    const float* Wpost0 = (const float*)d_in[14];
    const float* bpost0 = (const float*)d_in[15];
    const float* Wpost1 = (const float*)d_in[16];
    const float* bpost1 = (const float*)d_in[17];
    float* out = (float*)d_out;

    const int N = in_sizes[0];       // 160000
    const int E = in_sizes[2];       // 2560000
    const int G = out_size;          // 1024
    const int nb = (N + 255) / 256;

    const int* row = ei;
    const int* col = ei + E;

    // ---- workspace layout (floats) ----
    float* ws = (float*)d_ws;
    size_t nd = (size_t)N * DIM;
    float*          agg    = ws;                              // nd fp32
    unsigned short* xwb    = (unsigned short*)(agg + nd);     // nd bf16 = nd/2 floats
    unsigned long long* packed = (unsigned long long*)(xwb + nd);  // N u64 (offset 1.5nd floats, even -> 8B ok)
    float*          sums   = (float*)(packed + N);            // G*DIM
    float*          gcnt   = sums + (size_t)G * DIM;          // G
    float*          dinv   = gcnt + G;                        // N
    int*            cursor = (int*)(dinv + N);                // N
    int*            ptr    = cursor + N;                      // N+2
    int*            bsum   = ptr + (N + 2);                   // nb (pad even)
    float2*         edat   = (float2*)(bsum + ((nb + 1) & ~1));  // E*2 floats
    int*            ecol   = (int*)(edat + E);                // E

    // zero: packed | sums | gcnt (contiguous)
    hipMemsetAsync(packed, 0, sizeof(unsigned long long) * N + sizeof(float) * ((size_t)G * DIM + G), stream);

    const int B = 256;
    int ndThreads = N * DIM;

    deg_cnt_kernel<<<(E + B - 1) / B, B, 0, stream>>>(col, ew, packed, E);
    unpack_kernel<<<(N + B - 1) / B, B, 0, stream>>>(packed, dinv, N);

    scan_block_kernel<<<nb, 256, 0, stream>>>(packed, ptr, bsum, N);
    scan_tops_kernel<<<1, 64, 0, stream>>>(bsum, ptr, nb, N);
    scan_add_kernel<<<(N + B - 1) / B, B, 0, stream>>>(ptr, bsum, cursor, N);
    sort_kernel<<<(E + B - 1) / B, B, 0, stream>>>(row, col, ew, dinv, cursor, edat, ecol, E);

    // pre-MLP + xw0 + agg init
    pre_kernel<<<(ndThreads + B - 1) / B, B, 0, stream>>>(
        x, Wpre0, bpre0, Wpre1, bpre1, Wg[0], bg[0], dinv, xwb, agg, N);

    // edge-parallel grid: 16 threads per edge
    long long eThreads = (long long)((E + 3) / 4) * 64;
    int eBlocks = (int)((eThreads + B - 1) / B);

    // L0 edges
    edge_kernel<<<eBlocks, B, 0, stream>>>(xwb, edat, ecol, agg, E);
    // boundary -> L1
    mid_kernel<<<(ndThreads + B - 1) / B, B, 0, stream>>>(agg, Wg[1], bg[1], dinv, xwb, N);
    edge_kernel<<<eBlocks, B, 0, stream>>>(xwb, edat, ecol, agg, E);
    // boundary -> L2
    mid_kernel<<<(ndThreads + B - 1) / B, B, 0, stream>>>(agg, Wg[2], bg[2], dinv, xwb, N);
    edge_kernel<<<eBlocks, B, 0, stream>>>(xwb, edat, ecol, agg, E);

    // pool + post-MLP
    pool_kernel<<<(ndThreads + B - 1) / B, B, 0, stream>>>(agg, bat, sums, gcnt, N);
    postmlp_kernel<<<(G + B - 1) / B, B, 0, stream>>>(sums, gcnt, Wpost0, bpost0, Wpost1, bpost1, out, G);
}